// Round 3
// baseline (40188.153 us; speedup 1.0000x reference)
//
#include <hip/hip_runtime.h>
#include <hip/hip_bf16.h>
#include <hip/hip_cooperative_groups.h>

#define Bsz 256
#define Tlen 512
#define Dd 512
#define Hh 1024
#define G4 4096
#define NOUT 8
#define BT (Bsz * Tlen)

typedef short s16x8 __attribute__((ext_vector_type(8)));
typedef unsigned short u16x8 __attribute__((ext_vector_type(8)));
typedef float f32x4 __attribute__((ext_vector_type(4)));

__device__ __forceinline__ ushort f2bf(float f) {
    union { float f; uint u; } v; v.f = f;
    uint u = v.u;
    uint r = u + 0x7FFFu + ((u >> 16) & 1u);   // round-to-nearest-even
    return (ushort)(r >> 16);
}
__device__ __forceinline__ float bf2f(ushort u) {
    union { uint u; float f; } v; v.u = ((uint)u) << 16; return v.f;
}
__device__ __forceinline__ float sigf(float x) { return 1.f / (1.f + __expf(-x)); }
__device__ __forceinline__ float tanhfast(float x) {
    float ax = fabsf(x);
    float e = __expf(-2.f * ax);
    float t = (1.f - e) / (1.f + e);
    return copysignf(t, x);
}
__device__ __forceinline__ void gload16(const void* g, void* l) {
    __builtin_amdgcn_global_load_lds(
        (const __attribute__((address_space(1))) uint*)g,
        (__attribute__((address_space(3))) uint*)l, 16, 0, 0);
}

// ================= PREP KERNELS (main path) =================

// Reorder W_ih/W_hh fp32 -> bf16 MFMA B-fragments.
// fragbuf layout: group G = jt*192 + fbase(w) + f ; byte addr = G*1024 + lane*16
//   x-wave w in [0,4): fbase = w*16,  f = n*4 + ks (K=128 per wave)
//   h-wave w in [4,8): fbase = 64 + (w-4)*32, f = n*8 + ks (K=256 per wave)
// lane l holds B[col = n*16 + (l&15)][k0 + (l>>4)*8 .. +8], grow = n*1024 + jt*16 + (l&15)
__global__ void prep_frags(const float* __restrict__ Wih, const float* __restrict__ Whh,
                           ushort* __restrict__ fragbuf) {
    int gid = blockIdx.x * 256 + threadIdx.x;       // 786432 total
    int l = gid & 63;
    int G = gid >> 6;
    int jt = G / 192;
    int fi = G % 192;
    const float* src;
    int grow, k0;
    if (fi < 64) {
        int w = fi >> 4, f = fi & 15;
        int n = f >> 2, ks = f & 3;
        grow = n * 1024 + jt * 16 + (l & 15);
        k0 = w * 128 + ks * 32 + ((l >> 4) << 3);
        src = Wih + (size_t)grow * Dd + k0;
    } else {
        int fj = fi - 64;
        int w4 = fj >> 5, f = fj & 31;
        int n = f >> 3, ks = f & 7;
        grow = n * 1024 + jt * 16 + (l & 15);
        k0 = w4 * 256 + ks * 32 + ((l >> 4) << 3);
        src = Whh + (size_t)grow * Hh + k0;
    }
    u16x8 o;
    #pragma unroll
    for (int j = 0; j < 8; ++j) o[j] = f2bf(src[j]);
    *(u16x8*)(fragbuf + (size_t)gid * 8) = o;
}

// zero ring_h[0] (512 KB) and fill ring_x[0] with bf16(x[:, 0, :])
__global__ void init_rings(const float* __restrict__ x, uint4* __restrict__ ring_h,
                           ushort* __restrict__ ring_x) {
    int i = blockIdx.x * 256 + threadIdx.x;         // 32768 threads
    ring_h[i] = make_uint4(0u, 0u, 0u, 0u);
    if (i < 16384) {
        int row = i >> 6, kc = i & 63;
        const float* xs = x + (size_t)row * (Tlen * Dd) + kc * 8;   // t = 0
        float4 v0 = *(const float4*)xs;
        float4 v1 = *(const float4*)(xs + 4);
        u16x8 o;
        o[0]=f2bf(v0.x); o[1]=f2bf(v0.y); o[2]=f2bf(v0.z); o[3]=f2bf(v0.w);
        o[4]=f2bf(v1.x); o[5]=f2bf(v1.y); o[6]=f2bf(v1.z); o[7]=f2bf(v1.w);
        *(u16x8*)(ring_x + (size_t)row * Dd + kc * 8) = o;
    }
}

// ================= PERSISTENT LSTM KERNEL =================
// 256 blocks x 512 threads (8 waves, 2/SIMD). block = (bt = blk>>6, jt = blk&63)
// output tile: 64 batch rows x 64 gate-cols {g*1024 + jt*16 + cv}.
// waves 0-3: x-part, K=128 each, A from ring_x (global bf16).
// waves 4-7: h-part, K=256 each, A self-staged to own 32KB LDS via global_load_lds.
// B-fragments resident in VGPRs for the whole 512 steps.
// h ring stored SWIZZLED: chunk kc (16B) at position kc ^ (row&7) (low-3 XOR).
__launch_bounds__(512, 2)
__global__ void lstm_persistent(const float* __restrict__ x,
                                const ushort* __restrict__ fragbuf,
                                const float* __restrict__ b_ih,
                                const float* __restrict__ b_hh,
                                char* __restrict__ ring_h,     // 2 x 512 KB
                                ushort* __restrict__ ring_x) { // 2 x [256][512]
    __shared__ char lds_h[131072];
    __shared__ float c_lds[1024];
    __shared__ float bias_lds[64];

    const int tid  = threadIdx.x;
    const int lane = tid & 63;
    const int w    = tid >> 6;        // 0..7
    const bool is_h = (w >= 4);
    const int kg   = is_h ? (w - 4) : w;
    const int bt   = blockIdx.x >> 6;
    const int jt   = blockIdx.x & 63;
    const int b0   = bt * 64;

    // ---- load resident B-fragments ----
    s16x8 barr[32];
    {
        const int fbase = is_h ? (64 + kg * 32) : (kg * 16);
        const ushort* src = fragbuf + (((size_t)(jt * 192 + fbase)) << 9) + lane * 8;
        if (is_h) {
            #pragma unroll
            for (int f = 0; f < 32; ++f) barr[f] = *(const s16x8*)(src + f * 512);
        } else {
            #pragma unroll
            for (int f = 0; f < 16; ++f) barr[f] = *(const s16x8*)(src + f * 512);
        }
    }
    // ---- init c (LDS) and bias sums ----
    for (int i = tid; i < 1024; i += 512) c_lds[i] = 0.f;
    if (tid < 64) {
        int g = tid >> 4, cv = tid & 15;
        int gcol = g * 1024 + jt * 16 + cv;
        bias_lds[tid] = b_ih[gcol] + b_hh[gcol];
    }
    __syncthreads();

    auto grid = cooperative_groups::this_grid();
    float* bufs = (float*)lds_h;               // 4 x [64][68] f32 partial buffers

    for (int t = 0; t < Tlen; ++t) {
        const int p = t & 1;
        f32x4 acc[4][4] = {};

        // ---- phase 0: h-waves stage their LDS region; wave 3 prefetches x[t+1] ----
        if (is_h) {
            const char* gsrc = ring_h + (size_t)p * 524288 + bt * 131072;
            char* ldst = &lds_h[kg * 32768];
            #pragma unroll
            for (int i = 0; i < 32; ++i) {
                const char* ga = gsrc + (i * 2 + (lane >> 5)) * 2048 + ((kg * 32 + (lane & 31)) << 4);
                gload16(ga, ldst + i * 1024);
            }
        }
        float4 xv0, xv1;
        const bool dopf = (w == 3) && (t + 1 < Tlen);
        if (dopf) {
            const float* xs = x + ((size_t)(b0 + jt) * Tlen + (t + 1)) * Dd + lane * 8;
            xv0 = *(const float4*)xs;
            xv1 = *(const float4*)(xs + 4);
        }

        // ---- phase 1: MFMA ----
        if (!is_h) {
            const ushort* rx = ring_x + (size_t)p * 131072;
            #pragma unroll
            for (int ks = 0; ks < 4; ++ks) {
                s16x8 a[4];
                #pragma unroll
                for (int m = 0; m < 4; ++m) {
                    int row = b0 + m * 16 + (lane & 15);
                    int k = kg * 128 + ks * 32 + ((lane >> 4) << 3);
                    a[m] = *(const s16x8*)(rx + (size_t)row * Dd + k);
                }
                #pragma unroll
                for (int m = 0; m < 4; ++m)
                    #pragma unroll
                    for (int n = 0; n < 4; ++n)
                        acc[m][n] = __builtin_amdgcn_mfma_f32_16x16x32_bf16(a[m], barr[n * 4 + ks], acc[m][n], 0, 0, 0);
            }
        } else {
            asm volatile("s_waitcnt vmcnt(0)" ::: "memory");
            __builtin_amdgcn_sched_barrier(0);
            const char* reg = &lds_h[kg * 32768];
            #pragma unroll
            for (int ks = 0; ks < 8; ++ks) {
                s16x8 a[4];
                #pragma unroll
                for (int m = 0; m < 4; ++m) {
                    int row = m * 16 + (lane & 15);
                    int pos = ((ks << 2) + (lane >> 4)) ^ (row & 7);
                    a[m] = *(const s16x8*)(reg + row * 512 + pos * 16);
                }
                #pragma unroll
                for (int m = 0; m < 4; ++m)
                    #pragma unroll
                    for (int n = 0; n < 4; ++n)
                        acc[m][n] = __builtin_amdgcn_mfma_f32_16x16x32_bf16(a[m], barr[n * 8 + ks], acc[m][n], 0, 0, 0);
            }
        }
        __syncthreads();   // BAR1: all MFMA done, lds_h free for partial bufs

        // ---- phase 2: x-waves write partial buffers 0..3 ----
        if (!is_h) {
            float* bw = bufs + kg * (64 * 68);
            #pragma unroll
            for (int m = 0; m < 4; ++m)
                #pragma unroll
                for (int n = 0; n < 4; ++n)
                    #pragma unroll
                    for (int j = 0; j < 4; ++j) {
                        int row = m * 16 + ((lane >> 4) << 2) + j;
                        int col = n * 16 + (lane & 15);
                        bw[row * 68 + col] = acc[m][n][j];
                    }
        }
        __syncthreads();   // BAR2

        // ---- phase 3: h-waves accumulate into buffers; wave 3 writes x-ring ----
        if (is_h) {
            float* bw = bufs + kg * (64 * 68);
            #pragma unroll
            for (int m = 0; m < 4; ++m)
                #pragma unroll
                for (int n = 0; n < 4; ++n)
                    #pragma unroll
                    for (int j = 0; j < 4; ++j) {
                        int row = m * 16 + ((lane >> 4) << 2) + j;
                        int col = n * 16 + (lane & 15);
                        bw[row * 68 + col] += acc[m][n][j];
                    }
        }
        if (dopf) {
            u16x8 o;
            o[0]=f2bf(xv0.x); o[1]=f2bf(xv0.y); o[2]=f2bf(xv0.z); o[3]=f2bf(xv0.w);
            o[4]=f2bf(xv1.x); o[5]=f2bf(xv1.y); o[6]=f2bf(xv1.z); o[7]=f2bf(xv1.w);
            *(u16x8*)(ring_x + (size_t)(p ^ 1) * 131072 + (size_t)(b0 + jt) * Dd + lane * 8) = o;
        }
        __syncthreads();   // BAR3: partials complete

        // ---- phase 4: activations + cell update + h write (swizzled) ----
        if (tid < 128) {
            int row = tid >> 1, half = tid & 1;
            u16x8 hn;
            #pragma unroll
            for (int q = 0; q < 8; ++q) {
                int cv = half * 8 + q;
                float gi = 0.f, gf = 0.f, gg = 0.f, go = 0.f;
                #pragma unroll
                for (int b = 0; b < 4; ++b) {
                    const float* bb = bufs + b * (64 * 68) + row * 68;
                    gi += bb[cv]; gf += bb[16 + cv]; gg += bb[32 + cv]; go += bb[48 + cv];
                }
                gi += bias_lds[cv]; gf += bias_lds[16 + cv];
                gg += bias_lds[32 + cv]; go += bias_lds[48 + cv];
                float i_ = sigf(gi), f_ = sigf(gf), g_ = tanhfast(gg), o_ = sigf(go);
                float cn = f_ * c_lds[row * 16 + cv] + i_ * g_;
                c_lds[row * 16 + cv] = cn;
                hn[q] = f2bf(o_ * tanhfast(cn));
            }
            int pos = ((jt << 1) + half) ^ (row & 7);
            *(u16x8*)(ring_h + (size_t)(p ^ 1) * 524288 + bt * 131072 + row * 2048 + pos * 16) = hn;
        }
        __threadfence();
        grid.sync();
    }
}

// FC head over the swizzled final h (ring_h parity 0)
__global__ void fc_swz_kernel(const char* __restrict__ ring_h,
                              const float* __restrict__ Wfc,
                              const float* __restrict__ bfc,
                              float* __restrict__ out) {
    int b = blockIdx.x;
    int w = threadIdx.x >> 6;
    int lane = threadIdx.x & 63;
    int bt = b >> 6, row = b & 63;
    const char* hb = ring_h + bt * 131072 + row * 2048;
    float s = 0.f;
    #pragma unroll
    for (int kk = 0; kk < 2; ++kk) {
        int kc = lane + kk * 64;
        int pos = kc ^ (row & 7);
        const ushort* ch = (const ushort*)(hb + pos * 16);
        #pragma unroll
        for (int j = 0; j < 8; ++j) s += bf2f(ch[j]) * Wfc[w * Hh + kc * 8 + j];
    }
    #pragma unroll
    for (int off = 32; off; off >>= 1) s += __shfl_down(s, off);
    if (lane == 0) out[b * NOUT + w] = sigf(s + bfc[w]);
}

// ================= FALLBACK PATH (proven round-0/1) =================

__global__ void init_kernel(uint4* __restrict__ h0, uint4* __restrict__ c) {
    int i = blockIdx.x * 256 + threadIdx.x;
    uint4 z = make_uint4(0u, 0u, 0u, 0u);
    c[i] = z;
    if (i < 32768) h0[i] = z;
}

__global__ void cvt_kernel(const float4* __restrict__ src, ushort4* __restrict__ dst, int n4) {
    int i = blockIdx.x * 256 + threadIdx.x;
    if (i >= n4) return;
    float4 v = src[i];
    ushort4 o;
    o.x = f2bf(v.x); o.y = f2bf(v.y); o.z = f2bf(v.z); o.w = f2bf(v.w);
    dst[i] = o;
}

__launch_bounds__(256)
__global__ void lstm_step_fused(const float* __restrict__ x,
                          const ushort* __restrict__ Wih,
                          const ushort* __restrict__ Whh,
                          const float* __restrict__ b_ih,
                          const float* __restrict__ b_hh,
                          const ushort* __restrict__ h_prev,
                          ushort* __restrict__ h_next,
                          float* __restrict__ c,
                          int t) {
    __shared__ ushort At[64 * 64];
    __shared__ ushort Bt[64 * 64];
    __shared__ float gates[64 * 72];

    const int tid  = threadIdx.x;
    const int lane = tid & 63;
    const int wid  = tid >> 6;
    const int wr   = wid >> 1;
    const int wc   = wid & 1;
    const int bt   = blockIdx.x >> 6;
    const int jt   = blockIdx.x & 63;
    const int b0   = bt * 64;
    const int j0   = jt * 16;

    f32x4 acc[2][2] = {};

    auto mfma_tile = [&]() {
        #pragma unroll
        for (int ks = 0; ks < 2; ++ks) {
            const int kc = (ks << 2) + (lane >> 4);
            s16x8 a[2], bfr[2];
            #pragma unroll
            for (int m = 0; m < 2; ++m) {
                int row = wr * 32 + m * 16 + (lane & 15);
                a[m] = *(const s16x8*)&At[row * 64 + ((kc ^ (row & 7)) << 3)];
            }
            #pragma unroll
            for (int n = 0; n < 2; ++n) {
                int col = wc * 32 + n * 16 + (lane & 15);
                bfr[n] = *(const s16x8*)&Bt[col * 64 + ((kc ^ (col & 7)) << 3)];
            }
            #pragma unroll
            for (int m = 0; m < 2; ++m)
                #pragma unroll
                for (int n = 0; n < 2; ++n)
                    acc[m][n] = __builtin_amdgcn_mfma_f32_16x16x32_bf16(a[m], bfr[n], acc[m][n], 0, 0, 0);
        }
    };

    for (int kb = 0; kb < Dd; kb += 64) {
        __syncthreads();
        #pragma unroll
        for (int it = 0; it < 4; ++it) {
            int idx = tid + it * 256;
            int row = idx >> 4;
            int k   = (idx & 15) * 4;
            const float4 v = *(const float4*)&x[(size_t)(b0 + row) * (Tlen * Dd) + (size_t)t * Dd + kb + k];
            ushort4 o;
            o.x = f2bf(v.x); o.y = f2bf(v.y); o.z = f2bf(v.z); o.w = f2bf(v.w);
            int dst = row * 64 + (((k >> 3) ^ (row & 7)) << 3) + (k & 7);
            *(ushort4*)&At[dst] = o;
        }
        #pragma unroll
        for (int it = 0; it < 2; ++it) {
            int idx = tid + it * 256;
            int col = idx >> 3;
            int kc  = idx & 7;
            int grow = ((col >> 4) << 10) + j0 + (col & 15);
            uint4 v = *(const uint4*)&Wih[(size_t)grow * Dd + kb + kc * 8];
            *(uint4*)&Bt[col * 64 + ((kc ^ (col & 7)) << 3)] = v;
        }
        __syncthreads();
        mfma_tile();
    }
    for (int kb = 0; kb < Hh; kb += 64) {
        __syncthreads();
        #pragma unroll
        for (int it = 0; it < 2; ++it) {
            int idx = tid + it * 256;
            int row = idx >> 3;
            int kc  = idx & 7;
            uint4 v = *(const uint4*)&h_prev[(size_t)(b0 + row) * Hh + kb + kc * 8];
            *(uint4*)&At[row * 64 + ((kc ^ (row & 7)) << 3)] = v;
        }
        #pragma unroll
        for (int it = 0; it < 2; ++it) {
            int idx = tid + it * 256;
            int col = idx >> 3;
            int kc  = idx & 7;
            int grow = ((col >> 4) << 10) + j0 + (col & 15);
            uint4 v = *(const uint4*)&Whh[(size_t)grow * Hh + kb + kc * 8];
            *(uint4*)&Bt[col * 64 + ((kc ^ (col & 7)) << 3)] = v;
        }
        __syncthreads();
        mfma_tile();
    }

    #pragma unroll
    for (int m = 0; m < 2; ++m)
        #pragma unroll
        for (int n = 0; n < 2; ++n)
            #pragma unroll
            for (int j = 0; j < 4; ++j) {
                int row = wr * 32 + m * 16 + ((lane >> 4) << 2) + j;
                int col = wc * 32 + n * 16 + (lane & 15);
                gates[row * 72 + col] = acc[m][n][j];
            }
    __syncthreads();

    #pragma unroll
    for (int it = 0; it < 4; ++it) {
        int idx = tid + it * 256;
        int row = idx >> 4;
        int cc  = idx & 15;
        int gcol = j0 + cc;
        float gi = gates[row * 72 + cc]      + b_ih[gcol]          + b_hh[gcol];
        float gf = gates[row * 72 + 16 + cc] + b_ih[Hh + gcol]     + b_hh[Hh + gcol];
        float gg = gates[row * 72 + 32 + cc] + b_ih[2 * Hh + gcol] + b_hh[2 * Hh + gcol];
        float go = gates[row * 72 + 48 + cc] + b_ih[3 * Hh + gcol] + b_hh[3 * Hh + gcol];
        float i_ = sigf(gi);
        float f_ = sigf(gf);
        float g_ = tanhfast(gg);
        float o_ = sigf(go);
        size_t cidx = (size_t)(b0 + row) * Hh + gcol;
        float cn = f_ * c[cidx] + i_ * g_;
        c[cidx] = cn;
        float hn = o_ * tanhfast(cn);
        h_next[cidx] = f2bf(hn);
    }
}

__global__ void fc_kernel(const ushort* __restrict__ h,
                          const float* __restrict__ Wfc,
                          const float* __restrict__ bfc,
                          float* __restrict__ out) {
    int b = blockIdx.x;
    int w = threadIdx.x >> 6;
    int lane = threadIdx.x & 63;
    float s = 0.f;
    for (int k = lane; k < Hh; k += 64)
        s += bf2f(h[(size_t)b * Hh + k]) * Wfc[w * Hh + k];
    #pragma unroll
    for (int off = 32; off; off >>= 1) s += __shfl_down(s, off);
    if (lane == 0) out[b * NOUT + w] = sigf(s + bfc[w]);
}

// ================= LAUNCH =================

static void run_fallback(const float* x, const float* W_ih, const float* W_hh,
                         const float* b_ih, const float* b_hh,
                         const float* W_fc, const float* b_fc, float* out,
                         char* ws, hipStream_t stream) {
    ushort* h_buf  = (ushort*)ws;
    float*  c_ws   = (float*)(ws + (1ull << 20));
    ushort* wih_bf = (ushort*)(ws + (2ull << 20));
    ushort* whh_bf = (ushort*)(ws + (6ull << 20));

    init_kernel<<<256, 256, 0, stream>>>((uint4*)h_buf, (uint4*)c_ws);
    cvt_kernel<<<(G4 * Dd / 4) / 256, 256, 0, stream>>>((const float4*)W_ih, (ushort4*)wih_bf, G4 * Dd / 4);
    cvt_kernel<<<(G4 * Hh / 4) / 256, 256, 0, stream>>>((const float4*)W_hh, (ushort4*)whh_bf, G4 * Hh / 4);
    for (int t = 0; t < Tlen; ++t) {
        const ushort* hp = h_buf + (size_t)(t & 1) * Bsz * Hh;
        ushort*       hn = h_buf + (size_t)((t + 1) & 1) * Bsz * Hh;
        lstm_step_fused<<<256, 256, 0, stream>>>(x, wih_bf, whh_bf, b_ih, b_hh, hp, hn, c_ws, t);
    }
    fc_kernel<<<256, 512, 0, stream>>>(h_buf, W_fc, b_fc, out);
}

extern "C" void kernel_launch(void* const* d_in, const int* in_sizes, int n_in,
                              void* d_out, int out_size, void* d_ws, size_t ws_size,
                              hipStream_t stream) {
    const float* x    = (const float*)d_in[0];
    const float* W_ih = (const float*)d_in[1];
    const float* W_hh = (const float*)d_in[2];
    const float* b_ih = (const float*)d_in[3];
    const float* b_hh = (const float*)d_in[4];
    const float* W_fc = (const float*)d_in[5];
    const float* b_fc = (const float*)d_in[6];
    float* out = (float*)d_out;
    char* ws = (char*)d_ws;

    // main-path ws layout:
    //   [0, 1 MB)          ring_h: 2 x [4 bt][64 row][128 chunk swizzled] bf16
    //   [1 MB, 1.5 MB)     ring_x: 2 x [256][512] bf16
    //   [1.5 MB, 13.5 MB)  fragbuf: 64 jt x 192 frag-groups x 1 KB
    char*   ring_h  = ws;
    ushort* ring_x  = (ushort*)(ws + (1ull << 20));
    ushort* fragbuf = (ushort*)(ws + (1536ull << 10));
    const size_t MAIN_NEED = (1536ull << 10) + 12582912ull;   // 13.5 MB

    if (ws_size >= MAIN_NEED) {
        prep_frags<<<3072, 256, 0, stream>>>(W_ih, W_hh, fragbuf);
        init_rings<<<128, 256, 0, stream>>>(x, (uint4*)ring_h, ring_x);

        void* args[] = { (void*)&x, (void*)&fragbuf, (void*)&b_ih, (void*)&b_hh,
                         (void*)&ring_h, (void*)&ring_x };
        hipError_t err = hipLaunchCooperativeKernel((const void*)lstm_persistent,
                                                    dim3(256), dim3(512), args, 0, stream);
        if (err == hipSuccess) {
            fc_swz_kernel<<<256, 512, 0, stream>>>(ring_h, W_fc, b_fc, out);
            return;
        }
        // cooperative launch unsupported -> fall through to fallback
    }
    run_fallback(x, W_ih, W_hh, b_ih, b_hh, W_fc, b_fc, out, ws, stream);
}

// Round 4
// 5618.220 us; speedup vs baseline: 7.1532x; 7.1532x over previous
//
#include <hip/hip_runtime.h>
#include <hip/hip_bf16.h>

#define Bsz 256
#define Tlen 512
#define Dd 512
#define Hh 1024
#define G4 4096
#define NOUT 8
#define BT (Bsz * Tlen)

typedef short s16x8 __attribute__((ext_vector_type(8)));
typedef unsigned short u16x8 __attribute__((ext_vector_type(8)));
typedef float f32x4 __attribute__((ext_vector_type(4)));

__device__ __forceinline__ ushort f2bf(float f) {
    union { float f; uint u; } v; v.f = f;
    uint u = v.u;
    uint r = u + 0x7FFFu + ((u >> 16) & 1u);   // round-to-nearest-even
    return (ushort)(r >> 16);
}
__device__ __forceinline__ float bf2f(ushort u) {
    union { uint u; float f; } v; v.u = ((uint)u) << 16; return v.f;
}
__device__ __forceinline__ float sigf(float x) { return 1.f / (1.f + __expf(-x)); }
__device__ __forceinline__ float tanhfast(float x) {
    float ax = fabsf(x);
    float e = __expf(-2.f * ax);
    float t = (1.f - e) / (1.f + e);
    return copysignf(t, x);
}
__device__ __forceinline__ void gload16(const void* g, void* l) {
    __builtin_amdgcn_global_load_lds(
        (const __attribute__((address_space(1))) uint*)g,
        (__attribute__((address_space(3))) uint*)l, 16, 0, 0);
}

// ---------------- init: zero h0 (bf16, buffer 0) and c (fp32) ----------------
__global__ void init_kernel(uint4* __restrict__ h0, uint4* __restrict__ c) {
    int i = blockIdx.x * 256 + threadIdx.x;       // 65536 threads
    uint4 z = make_uint4(0u, 0u, 0u, 0u);
    c[i] = z;                                     // 1 MB
    if (i < 32768) h0[i] = z;                     // 512 KB
}

// ---------------- fp32 -> bf16 convert (layout-preserving) ----------------
__global__ void cvt_kernel(const float4* __restrict__ src, ushort4* __restrict__ dst, int n4) {
    int i = blockIdx.x * 256 + threadIdx.x;
    if (i >= n4) return;
    float4 v = src[i];
    ushort4 o;
    o.x = f2bf(v.x); o.y = f2bf(v.y); o.z = f2bf(v.z); o.w = f2bf(v.w);
    dst[i] = o;
}

// ---------------- chunk convert: x[:, t0..t0+7, :] fp32 -> [256][8][512] bf16 ----------------
__global__ void cvt_xchunk(const float* __restrict__ x, ushort* __restrict__ dst, int t0) {
    int gid = blockIdx.x * 256 + threadIdx.x;     // 131072 units of 8 elems
    int k8  = gid & 63;
    int tl  = (gid >> 6) & 7;
    int row = gid >> 9;                           // 0..255
    const float* s = x + ((size_t)row * Tlen + t0 + tl) * Dd + k8 * 8;
    float4 v0 = *(const float4*)s;
    float4 v1 = *(const float4*)(s + 4);
    u16x8 o;
    o[0]=f2bf(v0.x); o[1]=f2bf(v0.y); o[2]=f2bf(v0.z); o[3]=f2bf(v0.w);
    o[4]=f2bf(v1.x); o[5]=f2bf(v1.y); o[6]=f2bf(v1.z); o[7]=f2bf(v1.w);
    *(u16x8*)(dst + ((size_t)row * 8 + tl) * Dd + k8 * 8) = o;
}

// ---------------- one LSTM time step, K=1536, 4 K-groups x 2 waves ----------------
// grid 256 blocks x 512 threads. Block -> (bt, jt) via XCD-aware remap so the
// 4 bt-copies of each jt land on one XCD (W slice 1.5 MB -> L2-resident).
// Output tile: 64 batch rows x 64 gate-cols {g*1024 + jt*16 + cv}.
// K-group g covers k = g*384 .. +384 (6 chunks of 64): k<512 -> x_bf, else h_prev.
// Wave pair (2g, 2g+1): even wave stages A, odd stages B; both compute col-halves.
// LDS: 4 groups x 2 buf x (8KB A + 8KB B) = 128 KB; partials reuse same region.
__launch_bounds__(512, 2)
__global__ void lstm_step3(const ushort* __restrict__ xsrc, int tstride, int tloc,
                           const ushort* __restrict__ Wih,   // bf16 [4096][512]
                           const ushort* __restrict__ Whh,   // bf16 [4096][1024]
                           const ushort* __restrict__ h_prev,// bf16 [256][1024]
                           ushort* __restrict__ h_next,
                           float* __restrict__ c,            // fp32 [256][1024]
                           const float* __restrict__ b_ih,
                           const float* __restrict__ b_hh) {
    __shared__ char smem[131072];
    __shared__ float bias_lds[64];

    const int tid  = threadIdx.x;
    const int lane = tid & 63;
    const int w    = tid >> 6;       // 0..7
    const int g    = w >> 1;         // K-group 0..3
    const int ab   = w & 1;          // 0: stage A / cols 0..31, 1: stage B / cols 32..63

    const int B   = blockIdx.x;
    const int xcd  = B & 7, slot = B >> 3;     // heuristic XCD remap (perf only)
    const int jt   = xcd * 8 + (slot >> 2);    // 0..63
    const int bt   = slot & 3;                 // 0..3
    const int b0   = bt * 64;

    if (tid < 64) {
        int gcol = (tid >> 4) * 1024 + jt * 16 + (tid & 15);
        bias_lds[tid] = b_ih[gcol] + b_hh[gcol];
    }

    f32x4 acc[4][2] = {};

    auto STAGE = [&](int buf, int it) {
        const int k0 = (g * 6 + it) << 6;
        char* base = smem + g * 32768 + buf * 16384 + ab * 8192;
        if (ab == 0) {
            if (k0 < Dd) {
                #pragma unroll
                for (int q = 0; q < 8; ++q) {
                    int r  = q * 8 + (lane >> 3);
                    int cs = (lane & 7) ^ (r & 7);
                    const ushort* gp = xsrc + ((size_t)(b0 + r) * tstride + tloc) * Dd + k0 + cs * 8;
                    gload16(gp, base + q * 1024);
                }
            } else {
                #pragma unroll
                for (int q = 0; q < 8; ++q) {
                    int r  = q * 8 + (lane >> 3);
                    int cs = (lane & 7) ^ (r & 7);
                    const ushort* gp = h_prev + (size_t)(b0 + r) * Hh + (k0 - Dd) + cs * 8;
                    gload16(gp, base + q * 1024);
                }
            }
        } else {
            #pragma unroll
            for (int q = 0; q < 8; ++q) {
                int col = q * 8 + (lane >> 3);
                int cs  = (lane & 7) ^ (col & 7);
                int grow = (col >> 4) * 1024 + jt * 16 + (col & 15);
                const ushort* gp = (k0 < Dd)
                    ? (Wih + (size_t)grow * Dd + k0 + cs * 8)
                    : (Whh + (size_t)grow * Hh + (k0 - Dd) + cs * 8);
                gload16(gp, base + q * 1024);
            }
        }
    };
    auto COMPUTE = [&](int buf) {
        const char* Ab = smem + g * 32768 + buf * 16384;
        const char* Bb = Ab + 8192;
        #pragma unroll
        for (int ks = 0; ks < 2; ++ks) {
            const int kc = (ks << 2) + (lane >> 4);
            s16x8 a[4], bb[2];
            #pragma unroll
            for (int m = 0; m < 4; ++m) {
                int row = (m << 4) + (lane & 15);
                a[m] = *(const s16x8*)(Ab + row * 128 + ((kc ^ (row & 7)) << 4));
            }
            #pragma unroll
            for (int n = 0; n < 2; ++n) {
                int col = (ab << 5) + (n << 4) + (lane & 15);
                bb[n] = *(const s16x8*)(Bb + col * 128 + ((kc ^ (col & 7)) << 4));
            }
            #pragma unroll
            for (int m = 0; m < 4; ++m)
                #pragma unroll
                for (int n = 0; n < 2; ++n)
                    acc[m][n] = __builtin_amdgcn_mfma_f32_16x16x32_bf16(a[m], bb[n], acc[m][n], 0, 0, 0);
        }
    };

    STAGE(0, 0);
    __syncthreads();                 // drains vmcnt: buf0 ready
    #pragma unroll
    for (int it = 0; it < 6; ++it) {
        if (it < 5) STAGE((it + 1) & 1, it + 1);   // issue next-tile loads first
        COMPUTE(it & 1);
        __syncthreads();             // drains vmcnt: next buf ready, LDS safe
    }

    // ---- partials: group g -> LDS buffer g (reuse tile region) ----
    float* bw = (float*)smem + g * (64 * 68);
    #pragma unroll
    for (int m = 0; m < 4; ++m)
        #pragma unroll
        for (int n = 0; n < 2; ++n)
            #pragma unroll
            for (int j = 0; j < 4; ++j) {
                int row = (m << 4) + ((lane >> 4) << 2) + j;
                int col = (ab << 5) + (n << 4) + (lane & 15);
                bw[row * 68 + col] = acc[m][n][j];
            }
    __syncthreads();

    // ---- reduce 4 partials + activations + cell update ----
    const float* bufs = (const float*)smem;
    #pragma unroll
    for (int u = 0; u < 2; ++u) {
        int cell = tid * 2 + u;                // 0..1023
        int row  = cell >> 4;
        int cv   = cell & 15;
        float gi = 0.f, gf = 0.f, gg = 0.f, go = 0.f;
        #pragma unroll
        for (int p = 0; p < 4; ++p) {
            const float* bb = bufs + p * (64 * 68) + row * 68;
            gi += bb[cv]; gf += bb[16 + cv]; gg += bb[32 + cv]; go += bb[48 + cv];
        }
        gi += bias_lds[cv];      gf += bias_lds[16 + cv];
        gg += bias_lds[32 + cv]; go += bias_lds[48 + cv];
        float i_ = sigf(gi), f_ = sigf(gf), g_ = tanhfast(gg), o_ = sigf(go);
        int gcol = jt * 16 + cv;
        size_t cidx = (size_t)(b0 + row) * Hh + gcol;
        float cn = f_ * c[cidx] + i_ * g_;
        c[cidx] = cn;
        h_next[cidx] = f2bf(o_ * tanhfast(cn));
    }
}

// ---------------- FALLBACK: proven round-0 fused step ----------------
__launch_bounds__(256)
__global__ void lstm_step_fused(const float* __restrict__ x,
                          const ushort* __restrict__ Wih,
                          const ushort* __restrict__ Whh,
                          const float* __restrict__ b_ih,
                          const float* __restrict__ b_hh,
                          const ushort* __restrict__ h_prev,
                          ushort* __restrict__ h_next,
                          float* __restrict__ c,
                          int t) {
    __shared__ ushort At[64 * 64];
    __shared__ ushort Bt[64 * 64];
    __shared__ float gates[64 * 72];

    const int tid  = threadIdx.x;
    const int lane = tid & 63;
    const int wid  = tid >> 6;
    const int wr   = wid >> 1;
    const int wc   = wid & 1;
    const int bt   = blockIdx.x >> 6;
    const int jt   = blockIdx.x & 63;
    const int b0   = bt * 64;
    const int j0   = jt * 16;

    f32x4 acc[2][2] = {};

    auto mfma_tile = [&]() {
        #pragma unroll
        for (int ks = 0; ks < 2; ++ks) {
            const int kc = (ks << 2) + (lane >> 4);
            s16x8 a[2], bfr[2];
            #pragma unroll
            for (int m = 0; m < 2; ++m) {
                int row = wr * 32 + m * 16 + (lane & 15);
                a[m] = *(const s16x8*)&At[row * 64 + ((kc ^ (row & 7)) << 3)];
            }
            #pragma unroll
            for (int n = 0; n < 2; ++n) {
                int col = wc * 32 + n * 16 + (lane & 15);
                bfr[n] = *(const s16x8*)&Bt[col * 64 + ((kc ^ (col & 7)) << 3)];
            }
            #pragma unroll
            for (int m = 0; m < 2; ++m)
                #pragma unroll
                for (int n = 0; n < 2; ++n)
                    acc[m][n] = __builtin_amdgcn_mfma_f32_16x16x32_bf16(a[m], bfr[n], acc[m][n], 0, 0, 0);
        }
    };

    for (int kb = 0; kb < Dd; kb += 64) {
        __syncthreads();
        #pragma unroll
        for (int it = 0; it < 4; ++it) {
            int idx = tid + it * 256;
            int row = idx >> 4;
            int k   = (idx & 15) * 4;
            const float4 v = *(const float4*)&x[(size_t)(b0 + row) * (Tlen * Dd) + (size_t)t * Dd + kb + k];
            ushort4 o;
            o.x = f2bf(v.x); o.y = f2bf(v.y); o.z = f2bf(v.z); o.w = f2bf(v.w);
            int dst = row * 64 + (((k >> 3) ^ (row & 7)) << 3) + (k & 7);
            *(ushort4*)&At[dst] = o;
        }
        #pragma unroll
        for (int it = 0; it < 2; ++it) {
            int idx = tid + it * 256;
            int col = idx >> 3;
            int kc  = idx & 7;
            int grow = ((col >> 4) << 10) + j0 + (col & 15);
            uint4 v = *(const uint4*)&Wih[(size_t)grow * Dd + kb + kc * 8];
            *(uint4*)&Bt[col * 64 + ((kc ^ (col & 7)) << 3)] = v;
        }
        __syncthreads();
        mfma_tile();
    }
    for (int kb = 0; kb < Hh; kb += 64) {
        __syncthreads();
        #pragma unroll
        for (int it = 0; it < 2; ++it) {
            int idx = tid + it * 256;
            int row = idx >> 3;
            int kc  = idx & 7;
            uint4 v = *(const uint4*)&h_prev[(size_t)(b0 + row) * Hh + kb + kc * 8];
            *(uint4*)&At[row * 64 + ((kc ^ (row & 7)) << 3)] = v;
        }
        #pragma unroll
        for (int it = 0; it < 2; ++it) {
            int idx = tid + it * 256;
            int col = idx >> 3;
            int kc  = idx & 7;
            int grow = ((col >> 4) << 10) + j0 + (col & 15);
            uint4 v = *(const uint4*)&Whh[(size_t)grow * Hh + kb + kc * 8];
            *(uint4*)&Bt[col * 64 + ((kc ^ (col & 7)) << 3)] = v;
        }
        __syncthreads();
        mfma_tile();
    }

    #pragma unroll
    for (int m = 0; m < 2; ++m)
        #pragma unroll
        for (int n = 0; n < 2; ++n)
            #pragma unroll
            for (int j = 0; j < 4; ++j) {
                int row = wr * 32 + m * 16 + ((lane >> 4) << 2) + j;
                int col = wc * 32 + n * 16 + (lane & 15);
                gates[row * 72 + col] = acc[m][n][j];
            }
    __syncthreads();

    #pragma unroll
    for (int it = 0; it < 4; ++it) {
        int idx = tid + it * 256;
        int row = idx >> 4;
        int cc  = idx & 15;
        int gcol = j0 + cc;
        float gi = gates[row * 72 + cc]      + b_ih[gcol]          + b_hh[gcol];
        float gf = gates[row * 72 + 16 + cc] + b_ih[Hh + gcol]     + b_hh[Hh + gcol];
        float gg = gates[row * 72 + 32 + cc] + b_ih[2 * Hh + gcol] + b_hh[2 * Hh + gcol];
        float go = gates[row * 72 + 48 + cc] + b_ih[3 * Hh + gcol] + b_hh[3 * Hh + gcol];
        float i_ = sigf(gi);
        float f_ = sigf(gf);
        float g_ = tanhfast(gg);
        float o_ = sigf(go);
        size_t cidx = (size_t)(b0 + row) * Hh + gcol;
        float cn = f_ * c[cidx] + i_ * g_;
        c[cidx] = cn;
        float hn = o_ * tanhfast(cn);
        h_next[cidx] = f2bf(hn);
    }
}

// ---------------- FC head ----------------
__global__ void fc_kernel(const ushort* __restrict__ h,
                          const float* __restrict__ Wfc,
                          const float* __restrict__ bfc,
                          float* __restrict__ out) {
    int b = blockIdx.x;
    int w = threadIdx.x >> 6;
    int lane = threadIdx.x & 63;
    float s = 0.f;
    for (int k = lane; k < Hh; k += 64)
        s += bf2f(h[(size_t)b * Hh + k]) * Wfc[w * Hh + k];
    #pragma unroll
    for (int off = 32; off; off >>= 1) s += __shfl_down(s, off);
    if (lane == 0) out[b * NOUT + w] = sigf(s + bfc[w]);
}

// ================= LAUNCH =================

extern "C" void kernel_launch(void* const* d_in, const int* in_sizes, int n_in,
                              void* d_out, int out_size, void* d_ws, size_t ws_size,
                              hipStream_t stream) {
    const float* x    = (const float*)d_in[0];
    const float* W_ih = (const float*)d_in[1];
    const float* W_hh = (const float*)d_in[2];
    const float* b_ih = (const float*)d_in[3];
    const float* b_hh = (const float*)d_in[4];
    const float* W_fc = (const float*)d_in[5];
    const float* b_fc = (const float*)d_in[6];
    float* out = (float*)d_out;
    char* ws = (char*)d_ws;

    // ws layout (fixed part = 14 MB, proven available):
    //   [0, 1 MB)    h ping-pong bf16 [2][256][1024]
    //   [1, 2 MB)    c fp32 [256][1024]
    //   [2, 6 MB)    W_ih bf16 [4096][512]
    //   [6, 14 MB)   W_hh bf16 [4096][1024]
    //   [14 MB, ..)  x bf16: full [256][512][512] (128 MB, T1) or
    //                2 chunk buffers [256][8][512] (4 MB, T2)
    ushort* h_buf  = (ushort*)ws;
    float*  c_ws   = (float*)(ws + (1ull << 20));
    ushort* wih_bf = (ushort*)(ws + (2ull << 20));
    ushort* whh_bf = (ushort*)(ws + (6ull << 20));
    char*   x_ext  = ws + (14ull << 20);

    const size_t FIXED   = 14ull << 20;
    const size_t XFULL   = (size_t)Bsz * Tlen * Dd * 2;        // 128 MB
    const size_t XCHUNK  = (size_t)Bsz * 8 * Dd * 2;           // 2 MB per buffer

    init_kernel<<<256, 256, 0, stream>>>((uint4*)h_buf, (uint4*)c_ws);
    cvt_kernel<<<(G4 * Dd / 4) / 256, 256, 0, stream>>>((const float4*)W_ih, (ushort4*)wih_bf, G4 * Dd / 4);
    cvt_kernel<<<(G4 * Hh / 4) / 256, 256, 0, stream>>>((const float4*)W_hh, (ushort4*)whh_bf, G4 * Hh / 4);

    if (ws_size >= FIXED + XFULL) {
        // T1: convert all of x once; layout [b][t][k] (tstride=512)
        ushort* x_bf = (ushort*)x_ext;
        const int n4 = BT * Dd / 4;
        cvt_kernel<<<n4 / 256, 256, 0, stream>>>((const float4*)x, (ushort4*)x_bf, n4);
        for (int t = 0; t < Tlen; ++t) {
            const ushort* hp = h_buf + (size_t)(t & 1) * Bsz * Hh;
            ushort*       hn = h_buf + (size_t)((t + 1) & 1) * Bsz * Hh;
            lstm_step3<<<256, 512, 0, stream>>>(x_bf, Tlen, t, wih_bf, whh_bf,
                                                hp, hn, c_ws, b_ih, b_hh);
        }
    } else if (ws_size >= FIXED + 2 * XCHUNK) {
        // T2: double-buffered 8-step chunks; layout [b][8][k] (tstride=8)
        ushort* xchunk = (ushort*)x_ext;
        for (int t = 0; t < Tlen; ++t) {
            if ((t & 7) == 0) {
                ushort* dst = xchunk + (size_t)((t >> 3) & 1) * (Bsz * 8 * Dd);
                cvt_xchunk<<<512, 256, 0, stream>>>(x, dst, t);
            }
            const ushort* xb = xchunk + (size_t)((t >> 3) & 1) * (Bsz * 8 * Dd);
            const ushort* hp = h_buf + (size_t)(t & 1) * Bsz * Hh;
            ushort*       hn = h_buf + (size_t)((t + 1) & 1) * Bsz * Hh;
            lstm_step3<<<256, 512, 0, stream>>>(xb, 8, t & 7, wih_bf, whh_bf,
                                                hp, hn, c_ws, b_ih, b_hh);
        }
    } else {
        // T3: proven fallback
        for (int t = 0; t < Tlen; ++t) {
            const ushort* hp = h_buf + (size_t)(t & 1) * Bsz * Hh;
            ushort*       hn = h_buf + (size_t)((t + 1) & 1) * Bsz * Hh;
            lstm_step_fused<<<256, 256, 0, stream>>>(x, wih_bf, whh_bf, b_ih, b_hh, hp, hn, c_ws, t);
        }
    }
    // 512 steps (even) -> final h in buffer 0
    fc_kernel<<<256, 512, 0, stream>>>(h_buf, W_fc, b_fc, out);
}